// Round 3
// baseline (248.920 us; speedup 1.0000x reference)
//
#include <hip/hip_runtime.h>

namespace {

constexpr int BD = 2;
constexpr int DD = 160, HH = 192, WW = 224;
constexpr float INV_WIN = 1.0f / 729.0f;
constexpr float EPSV = 1e-5f;

constexpr int TH = 16, TW = 16;          // output tile (H x W)
constexpr int DC = 32;                   // output planes per d-chunk
constexpr int NREAL = DC + 8;            // 40 plane steps
constexpr int NCH = DD / DC;             // 5
constexpr int GX = WW / TW;              // 14
constexpr int GY = HH / TH;              // 12
constexpr int GZ = BD * NCH;             // 10
constexpr int NBLK = GX * GY * GZ;       // 1680
constexpr double NTOT = (double)BD * DD * HH * WW;

// srowF: 5 fields x 24 rows x (16 cols + pad). row stride 20 floats,
// field stride 516 (= 24*20+36): 516 % 32 == 4 spreads fields across banks,
// 516 % 4 == 0 keeps float4 alignment.
constexpr int SR_RS = 20;
constexpr int SR_FS = 516;
constexpr int SR_SZ = 4 * SR_FS + 24 * SR_RS;   // 2544 floats
// scolF: 5 fields x 16 rows x (16 cols + pad). field stride 356 (%32==4).
constexpr int SC_RS = 20;
constexpr int SC_FS = 356;
constexpr int SC_SZ = 4 * SC_FS + 16 * SC_RS;   // 1744 floats

} // namespace

__device__ __forceinline__ float4 f4add(float4 a, float4 b) {
  return make_float4(a.x + b.x, a.y + b.y, a.z + b.z, a.w + b.w);
}
__device__ __forceinline__ float4 f4sub(float4 a, float4 b) {
  return make_float4(a.x - b.x, a.y - b.y, a.z - b.z, a.w - b.w);
}

__global__ __launch_bounds__(256)
void ncc_fused(const float* __restrict__ x, const float* __restrict__ y,
               float* __restrict__ bsum) {
  const int tid = threadIdx.x;
  const int w0 = blockIdx.x * TW;
  const int h0 = blockIdx.y * TH;
  const int zb = blockIdx.z;
  const int b  = zb / NCH;
  const int d0 = (zb - b * NCH) * DC;

  __shared__ __align__(16) float srowF[SR_SZ];
  __shared__ __align__(16) float scolF[SC_SZ];
  __shared__ float swsum[4];

  // ---- S2 role geometry: 96 threads own (row rr, 4-col segment seg)
  const bool s2role = tid < 96;
  const int rr  = tid >> 2;          // 0..23
  const int seg = tid & 3;           // 0..3
  const int gh  = h0 - 4 + rr;
  const int gw0 = w0 - 4 + seg * 4;  // 16B aligned (w0 multiple of 16)
  const bool hok = (unsigned)gh < (unsigned)HH;
  const bool fastw = (gw0 >= 0) && (gw0 + 11 < WW);  // whole 12-wide window in range
  const unsigned planes = (unsigned)HH * WW;

  auto prefetch = [&](int s, float4* vx, float4* vy) {
    const int din = d0 - 4 + s;
    const float4 z = make_float4(0.f, 0.f, 0.f, 0.f);
    vx[0] = vx[1] = vx[2] = z;
    vy[0] = vy[1] = vy[2] = z;
    if (s2role && hok && (s < NREAL) && (din >= 0) && (din < DD)) {
      const unsigned rb = ((unsigned)b * DD + (unsigned)din) * planes + (unsigned)gh * WW;
      if (fastw) {
        const float4* px = (const float4*)(x + rb + gw0);
        const float4* py = (const float4*)(y + rb + gw0);
        vx[0] = px[0]; vx[1] = px[1]; vx[2] = px[2];
        vy[0] = py[0]; vy[1] = py[1]; vy[2] = py[2];
      } else {
        float* fx = (float*)vx;
        float* fy = (float*)vy;
#pragma unroll
        for (int e = 0; e < 12; ++e) {
          const int gw = gw0 + e;
          if ((unsigned)gw < (unsigned)WW) {
            fx[e] = x[rb + gw];
            fy[e] = y[rb + gw];
          }
        }
      }
    }
  };

  const int ow = tid & 15;
  const int oh = tid >> 4;

  // D-direction ring buffers (9 planes x 5 fields) in registers; static
  // indexing guaranteed by the fully-unrolled inner j-loop.
  float r0[9], r1[9], r2[9], r3[9], r4[9];
#pragma unroll
  for (int j = 0; j < 9; ++j) { r0[j]=0.f; r1[j]=0.f; r2[j]=0.f; r3[j]=0.f; r4[j]=0.f; }
  float a0=0.f, a1=0.f, a2=0.f, a3=0.f, a4=0.f;
  float lsum = 0.0f;

  float4 px4[3], py4[3];
  prefetch(0, px4, py4);

  for (int base = 0; base < 45; base += 9) {
#pragma unroll
    for (int j = 0; j < 9; ++j) {
      const int step = base + j;
      if (step < NREAL) {
        // issue next plane's global loads (latency hidden behind S2-S4)
        float4 nx4[3], ny4[3];
        prefetch(step + 1, nx4, ny4);

        // ---- S2: per-thread 12-wide window -> 4 sliding 9-tap W-sums x 5 fields
        if (s2role) {
          float xv[12], yv[12];
#pragma unroll
          for (int k = 0; k < 3; ++k) {
            *(float4*)&xv[4 * k] = px4[k];
            *(float4*)&yv[4 * k] = py4[k];
          }
          float s0=0.f, s1=0.f, s2=0.f, s3=0.f, s4=0.f;
#pragma unroll
          for (int k = 0; k < 9; ++k) {
            s0 += xv[k]; s1 += yv[k];
            s2 = fmaf(xv[k], xv[k], s2);
            s3 = fmaf(yv[k], yv[k], s3);
            s4 = fmaf(xv[k], yv[k], s4);
          }
          float o0[4], o1[4], o2[4], o3[4], o4[4];
          o0[0]=s0; o1[0]=s1; o2[0]=s2; o3[0]=s3; o4[0]=s4;
#pragma unroll
          for (int t = 0; t < 3; ++t) {
            const float xn = xv[9 + t], xo = xv[t];
            const float yn = yv[9 + t], yo = yv[t];
            s0 += xn - xo;
            s1 += yn - yo;
            s2 += fmaf(xn, xn, -(xo * xo));
            s3 += fmaf(yn, yn, -(yo * yo));
            s4 += fmaf(xn, yn, -(xo * yo));
            o0[t+1]=s0; o1[t+1]=s1; o2[t+1]=s2; o3[t+1]=s3; o4[t+1]=s4;
          }
          const int rb = rr * SR_RS + seg * 4;
          *(float4*)&srowF[0 * SR_FS + rb] = make_float4(o0[0], o0[1], o0[2], o0[3]);
          *(float4*)&srowF[1 * SR_FS + rb] = make_float4(o1[0], o1[1], o1[2], o1[3]);
          *(float4*)&srowF[2 * SR_FS + rb] = make_float4(o2[0], o2[1], o2[2], o2[3]);
          *(float4*)&srowF[3 * SR_FS + rb] = make_float4(o3[0], o3[1], o3[2], o3[3]);
          *(float4*)&srowF[4 * SR_FS + rb] = make_float4(o4[0], o4[1], o4[2], o4[3]);
        }
        __syncthreads();   // B: srowF visible

        // ---- S3: sliding 9-tap H-sums; 80 threads = 4 col-quads x 5 fields x 4 row-quarters
        if (tid < 80) {
          const int q  = tid / 20;                // row quarter, o0 = 4q
          const int f  = (tid - q * 20) >> 2;     // field
          const int w4 = tid & 3;                 // column quad
          const int o0 = q * 4;
          const float* rp = &srowF[f * SR_FS + w4 * 4];
          float4 s = make_float4(0.f, 0.f, 0.f, 0.f);
#pragma unroll
          for (int t = 0; t < 8; ++t)
            s = f4add(s, *(const float4*)&rp[(o0 + t) * SR_RS]);
#pragma unroll
          for (int t = 0; t < 4; ++t) {
            const int o = o0 + t;
            s = f4add(s, *(const float4*)&rp[(o + 8) * SR_RS]);
            *(float4*)&scolF[f * SC_FS + o * SC_RS + w4 * 4] = s;
            s = f4sub(s, *(const float4*)&rp[o * SR_RS]);
          }
        }
        __syncthreads();   // C: scolF visible

        // ---- S4: per-thread D ring update + emit (all 256 threads)
        const float g0 = scolF[0 * SC_FS + oh * SC_RS + ow];
        const float g1 = scolF[1 * SC_FS + oh * SC_RS + ow];
        const float g2 = scolF[2 * SC_FS + oh * SC_RS + ow];
        const float g3 = scolF[3 * SC_FS + oh * SC_RS + ow];
        const float g4 = scolF[4 * SC_FS + oh * SC_RS + ow];
        a0 += g0 - r0[j]; r0[j] = g0;
        a1 += g1 - r1[j]; r1[j] = g1;
        a2 += g2 - r2[j]; r2[j] = g2;
        a3 += g3 - r3[j]; r3[j] = g3;
        a4 += g4 - r4[j]; r4[j] = g4;
        if (step >= 8) {
          const float cross = fmaf(-a0 * INV_WIN, a1, a4);
          const float iv = fmaxf(fmaf(-a0 * INV_WIN, a0, a2), EPSV);
          const float jv = fmaxf(fmaf(-a1 * INV_WIN, a1, a3), EPSV);
          lsum += (cross * cross) / (iv * jv);
        }
        // WAR safety: next step's srowF writes happen after this step's
        // barrier C (every S2 thread passes C before writing), and S3's
        // srowF reads completed before C. scolF writes of step s+1 happen
        // after barrier B(s+1), which is after all S4(s) reads.
#pragma unroll
        for (int k = 0; k < 3; ++k) { px4[k] = nx4[k]; py4[k] = ny4[k]; }
      }
    }
  }

  // ---- block reduction
#pragma unroll
  for (int off = 32; off > 0; off >>= 1) lsum += __shfl_down(lsum, off);
  if ((tid & 63) == 0) swsum[tid >> 6] = lsum;
  __syncthreads();
  if (tid == 0) {
    const int bid = ((int)blockIdx.z * GY + (int)blockIdx.y) * GX + (int)blockIdx.x;
    bsum[bid] = swsum[0] + swsum[1] + swsum[2] + swsum[3];
  }
}

__global__ __launch_bounds__(256)
void ncc_finalize(const float* __restrict__ bsum, float* __restrict__ out) {
  double s = 0.0;
  for (int i = threadIdx.x; i < NBLK; i += 256) s += (double)bsum[i];
#pragma unroll
  for (int off = 32; off > 0; off >>= 1) s += __shfl_down(s, off);
  __shared__ double sh[4];
  if ((threadIdx.x & 63) == 0) sh[threadIdx.x >> 6] = s;
  __syncthreads();
  if (threadIdx.x == 0)
    out[0] = (float)(-(sh[0] + sh[1] + sh[2] + sh[3]) / NTOT);
}

extern "C" void kernel_launch(void* const* d_in, const int* in_sizes, int n_in,
                              void* d_out, int out_size, void* d_ws, size_t ws_size,
                              hipStream_t stream) {
  const float* x = (const float*)d_in[0];
  const float* y = (const float*)d_in[1];
  float* bsum = (float*)d_ws;          // 1680 floats, rewritten every call
  float* out  = (float*)d_out;

  dim3 grid(GX, GY, GZ);
  ncc_fused<<<grid, dim3(256), 0, stream>>>(x, y, bsum);
  ncc_finalize<<<1, dim3(256), 0, stream>>>(bsum, out);
}

// Round 4
// 227.180 us; speedup vs baseline: 1.0957x; 1.0957x over previous
//
#include <hip/hip_runtime.h>

namespace {

constexpr int BD = 2;
constexpr int DD = 160, HH = 192, WW = 224;
constexpr float INV_WIN = 1.0f / 729.0f;
constexpr float EPSV = 1e-5f;

constexpr int TH = 16, TW = 16;          // output tile (H x W)
constexpr int DC = 16;                   // output planes per d-chunk
constexpr int NREAL = DC + 8;            // 24 plane steps
constexpr int NSS = NREAL / 2;           // 12 supersteps (2 planes each)
constexpr int NCH = DD / DC;             // 10
constexpr int GX = WW / TW;              // 14
constexpr int GY = HH / TH;              // 12
constexpr int GZ = BD * NCH;             // 20
constexpr int NBLK = GX * GY * GZ;       // 3360
constexpr double NTOT = (double)BD * DD * HH * WW;

// srow: per plane, [field][row*20 + w4quad*4 + i]. Field stride 488 %32==8
// (avoids colliding with the quad stride 4); row stride 20.
constexpr int SR_RS = 20;
constexpr int SR_FS = 488;
constexpr int SR_PL = 5 * SR_FS;         // 2440 floats per plane
// scol: per plane, [o][ow][f] flattened as o*85 + ow*5 + f. Row stride 85
// (odd mod 32 -> o and oh spread banks); field stride 1, col stride 5
// (gcd(5,32)=1 -> S4's 64-lane scalar reads are exactly 2-way = free).
constexpr int SC_RS = 85;
constexpr int SC_PL = 16 * SC_RS;        // 1360 floats per plane

} // namespace

__device__ __forceinline__ float4 f4add(float4 a, float4 b) {
  return make_float4(a.x + b.x, a.y + b.y, a.z + b.z, a.w + b.w);
}
__device__ __forceinline__ float4 f4sub(float4 a, float4 b) {
  return make_float4(a.x - b.x, a.y - b.y, a.z - b.z, a.w - b.w);
}

__global__ __launch_bounds__(256)
void ncc_fused(const float* __restrict__ x, const float* __restrict__ y,
               float* __restrict__ bsum) {
  const int tid = threadIdx.x;
  const int w0 = blockIdx.x * TW;
  const int h0 = blockIdx.y * TH;
  const int zb = blockIdx.z;
  const int b  = zb / NCH;
  const int d0 = (zb - b * NCH) * DC;

  __shared__ __align__(16) float srowF[2 * SR_PL];
  __shared__ float scolF[2 * SC_PL];
  __shared__ float swsum[4];

  // ---- S2 roles: 192 threads = 2 planes x 24 rows x 4 col-segments
  const bool s2a = tid < 192;
  const int p2  = tid / 96;            // which plane of the superstep I stage
  const int t96 = tid - p2 * 96;
  const int r2  = t96 >> 2;            // input row 0..23
  const int seg = tid & 3;
  const int gh  = h0 - 4 + r2;
  const int gw0 = w0 - 4 + seg * 4;    // 16B aligned
  const bool hok = (unsigned)gh < (unsigned)HH;
  const bool fastw = (gw0 >= 0) && (gw0 + 11 < WW);
  const unsigned plane = (unsigned)HH * WW;

  auto prefetch = [&](int s, float4* vx, float4* vy) {
    const int din = d0 - 4 + s;
    const float4 z = make_float4(0.f, 0.f, 0.f, 0.f);
    vx[0] = vx[1] = vx[2] = z;
    vy[0] = vy[1] = vy[2] = z;
    if (s2a && hok && (s < NREAL) && (din >= 0) && (din < DD)) {
      const unsigned rb = ((unsigned)b * DD + (unsigned)din) * plane + (unsigned)gh * WW;
      if (fastw) {
        const float4* px = (const float4*)(x + rb + gw0);
        const float4* py = (const float4*)(y + rb + gw0);
        vx[0] = px[0]; vx[1] = px[1]; vx[2] = px[2];
        vy[0] = py[0]; vy[1] = py[1]; vy[2] = py[2];
      } else {
        float* fx = (float*)vx;
        float* fy = (float*)vy;
#pragma unroll
        for (int e = 0; e < 12; ++e) {
          const int gw = gw0 + e;
          if ((unsigned)gw < (unsigned)WW) {
            fx[e] = x[rb + gw];
            fy[e] = y[rb + gw];
          }
        }
      }
    }
  };

  const int ow = tid & 15;
  const int oh = tid >> 4;

  // D-ring: 9 planes x 5 fields, rotate-by-2 per superstep (static indices).
  float rg0[9], rg1[9], rg2[9], rg3[9], rg4[9];
#pragma unroll
  for (int k = 0; k < 9; ++k) { rg0[k]=0.f; rg1[k]=0.f; rg2[k]=0.f; rg3[k]=0.f; rg4[k]=0.f; }
  float a0=0.f, a1=0.f, a2=0.f, a3=0.f, a4=0.f;
  float lsum = 0.0f;

  float4 px4[3], py4[3];
  prefetch(p2, px4, py4);               // planes 0 (p2=0) and 1 (p2=1)

  for (int ss = 0; ss < NSS; ++ss) {
    // issue next superstep's plane loads early
    float4 nx4[3], ny4[3];
    prefetch(2 * (ss + 1) + p2, nx4, ny4);

    // ---- S2: 12-wide window -> 4 sliding 9-tap W-sums x 5 fields (192 thr)
    if (s2a) {
      float xv[12], yv[12];
#pragma unroll
      for (int k = 0; k < 3; ++k) {
        *(float4*)&xv[4 * k] = px4[k];
        *(float4*)&yv[4 * k] = py4[k];
      }
      float s0=0.f, s1=0.f, s2=0.f, s3=0.f, s4=0.f;
#pragma unroll
      for (int k = 0; k < 9; ++k) {
        s0 += xv[k]; s1 += yv[k];
        s2 = fmaf(xv[k], xv[k], s2);
        s3 = fmaf(yv[k], yv[k], s3);
        s4 = fmaf(xv[k], yv[k], s4);
      }
      float o0[4], o1[4], o2[4], o3[4], o4[4];
      o0[0]=s0; o1[0]=s1; o2[0]=s2; o3[0]=s3; o4[0]=s4;
#pragma unroll
      for (int t = 0; t < 3; ++t) {
        const float xn = xv[9 + t], xo = xv[t];
        const float yn = yv[9 + t], yo = yv[t];
        s0 += xn - xo;
        s1 += yn - yo;
        s2 += fmaf(xn, xn, -(xo * xo));
        s3 += fmaf(yn, yn, -(yo * yo));
        s4 += fmaf(xn, yn, -(xo * yo));
        o0[t+1]=s0; o1[t+1]=s1; o2[t+1]=s2; o3[t+1]=s3; o4[t+1]=s4;
      }
      const int rb = p2 * SR_PL + r2 * SR_RS + seg * 4;
      *(float4*)&srowF[rb + 0 * SR_FS] = make_float4(o0[0], o0[1], o0[2], o0[3]);
      *(float4*)&srowF[rb + 1 * SR_FS] = make_float4(o1[0], o1[1], o1[2], o1[3]);
      *(float4*)&srowF[rb + 2 * SR_FS] = make_float4(o2[0], o2[1], o2[2], o2[3]);
      *(float4*)&srowF[rb + 3 * SR_FS] = make_float4(o3[0], o3[1], o3[2], o3[3]);
      *(float4*)&srowF[rb + 4 * SR_FS] = make_float4(o4[0], o4[1], o4[2], o4[3]);
    }
    __syncthreads();   // B: srow visible

    // ---- S3: sliding 9-tap H-sums (160 thr = 2 planes x 4 q x 5 f x 4 quads)
    if (tid < 160) {
      const int p3  = tid / 80;
      const int r3  = tid - p3 * 80;
      const int q   = r3 / 20;
      const int rem = r3 - q * 20;
      const int f3  = rem >> 2;
      const int w43 = rem & 3;
      const int o0q = q * 4;
      const float* rp = &srowF[p3 * SR_PL + f3 * SR_FS + w43 * 4];
      float4 keep[4];
      float4 s = make_float4(0.f, 0.f, 0.f, 0.f);
#pragma unroll
      for (int t = 0; t < 8; ++t) {
        const float4 v = *(const float4*)&rp[(o0q + t) * SR_RS];
        if (t < 4) keep[t] = v;          // subtract terms kept in regs
        s = f4add(s, v);
      }
      float* cp = &scolF[p3 * SC_PL + w43 * 20 + f3];
#pragma unroll
      for (int t = 0; t < 4; ++t) {
        const int o = o0q + t;
        s = f4add(s, *(const float4*)&rp[(o + 8) * SR_RS]);
        float* c = cp + o * SC_RS;
        c[0] = s.x; c[5] = s.y; c[10] = s.z; c[15] = s.w;
        s = f4sub(s, keep[t]);
      }
    }
    __syncthreads();   // C: scol visible

    // ---- S4: ring update for both planes + emit (all 256 threads)
    const float* cA = &scolF[oh * SC_RS + ow * 5];
    const float* cB = cA + SC_PL;
    const float gA0=cA[0], gA1=cA[1], gA2=cA[2], gA3=cA[3], gA4=cA[4];
    const float gB0=cB[0], gB1=cB[1], gB2=cB[2], gB3=cB[3], gB4=cB[4];

    a0 += gA0 - rg0[0]; a1 += gA1 - rg1[0]; a2 += gA2 - rg2[0];
    a3 += gA3 - rg3[0]; a4 += gA4 - rg4[0];
    if (ss >= 4) {
      const float cross = fmaf(-a0 * INV_WIN, a1, a4);
      const float iv = fmaxf(fmaf(-a0 * INV_WIN, a0, a2), EPSV);
      const float jv = fmaxf(fmaf(-a1 * INV_WIN, a1, a3), EPSV);
      lsum += (cross * cross) / (iv * jv);
    }
    a0 += gB0 - rg0[1]; a1 += gB1 - rg1[1]; a2 += gB2 - rg2[1];
    a3 += gB3 - rg3[1]; a4 += gB4 - rg4[1];
    if (ss >= 4) {
      const float cross = fmaf(-a0 * INV_WIN, a1, a4);
      const float iv = fmaxf(fmaf(-a0 * INV_WIN, a0, a2), EPSV);
      const float jv = fmaxf(fmaf(-a1 * INV_WIN, a1, a3), EPSV);
      lsum += (cross * cross) / (iv * jv);
    }
    // rotate ring by 2
#pragma unroll
    for (int k = 0; k < 7; ++k) {
      rg0[k]=rg0[k+2]; rg1[k]=rg1[k+2]; rg2[k]=rg2[k+2];
      rg3[k]=rg3[k+2]; rg4[k]=rg4[k+2];
    }
    rg0[7]=gA0; rg1[7]=gA1; rg2[7]=gA2; rg3[7]=gA3; rg4[7]=gA4;
    rg0[8]=gB0; rg1[8]=gB1; rg2[8]=gB2; rg3[8]=gB3; rg4[8]=gB4;

    // WAR safety: srow(s+1) writes happen after every thread passed C(s);
    // scol(s) reads (S4) complete before any thread reaches B(s+1).
#pragma unroll
    for (int k = 0; k < 3; ++k) { px4[k] = nx4[k]; py4[k] = ny4[k]; }
  }

  // ---- block reduction
#pragma unroll
  for (int off = 32; off > 0; off >>= 1) lsum += __shfl_down(lsum, off);
  if ((tid & 63) == 0) swsum[tid >> 6] = lsum;
  __syncthreads();
  if (tid == 0) {
    const int bid = ((int)blockIdx.z * GY + (int)blockIdx.y) * GX + (int)blockIdx.x;
    bsum[bid] = swsum[0] + swsum[1] + swsum[2] + swsum[3];
  }
}

__global__ __launch_bounds__(256)
void ncc_finalize(const float* __restrict__ bsum, float* __restrict__ out) {
  double s = 0.0;
  for (int i = threadIdx.x; i < NBLK; i += 256) s += (double)bsum[i];
#pragma unroll
  for (int off = 32; off > 0; off >>= 1) s += __shfl_down(s, off);
  __shared__ double sh[4];
  if ((threadIdx.x & 63) == 0) sh[threadIdx.x >> 6] = s;
  __syncthreads();
  if (threadIdx.x == 0)
    out[0] = (float)(-(sh[0] + sh[1] + sh[2] + sh[3]) / NTOT);
}

extern "C" void kernel_launch(void* const* d_in, const int* in_sizes, int n_in,
                              void* d_out, int out_size, void* d_ws, size_t ws_size,
                              hipStream_t stream) {
  const float* x = (const float*)d_in[0];
  const float* y = (const float*)d_in[1];
  float* bsum = (float*)d_ws;          // 3360 floats, fully rewritten every call
  float* out  = (float*)d_out;

  dim3 grid(GX, GY, GZ);
  ncc_fused<<<grid, dim3(256), 0, stream>>>(x, y, bsum);
  ncc_finalize<<<1, dim3(256), 0, stream>>>(bsum, out);
}